// Round 5
// baseline (372.329 us; speedup 1.0000x reference)
//
#include <hip/hip_runtime.h>
#include <hip/hip_bf16.h>
#include <math.h>

#define B_SZ 256
#define F_SZ 2048
#define C_SZ 16384
#define P_SZ 8
#define N_SZ 32
#define NTILE 128   // one softmax partial per 128-col block slab

typedef __bf16 bf16x8 __attribute__((ext_vector_type(8)));
typedef float f32x4 __attribute__((ext_vector_type(4)));
typedef unsigned short us8 __attribute__((ext_vector_type(8)));

__device__ __forceinline__ unsigned short f2bf(float x) {
    union { float f; unsigned int u; } v; v.f = x;
    unsigned int r = v.u + 0x7FFFu + ((v.u >> 16) & 1u);  // RTN-even
    return (unsigned short)(r >> 16);
}

// ---------------- kernel 1: row norms + bf16 cast of inputs ----------------
__global__ __launch_bounds__(256) void prep_kernel(const float* __restrict__ inputs,
                                                   unsigned short* __restrict__ Abf,
                                                   float* __restrict__ norms) {
    const int row = blockIdx.x;
    const int tid = threadIdx.x;
    const float* rp = inputs + (size_t)row * F_SZ + tid * 8;
    float4 v0 = *(const float4*)(rp);
    float4 v1 = *(const float4*)(rp + 4);
    us8 o;
    o[0]=f2bf(v0.x); o[1]=f2bf(v0.y); o[2]=f2bf(v0.z); o[3]=f2bf(v0.w);
    o[4]=f2bf(v1.x); o[5]=f2bf(v1.y); o[6]=f2bf(v1.z); o[7]=f2bf(v1.w);
    *(us8*)(Abf + (size_t)row * F_SZ + tid * 8) = o;
    float ss = v0.x*v0.x + v0.y*v0.y + v0.z*v0.z + v0.w*v0.w
             + v1.x*v1.x + v1.y*v1.y + v1.z*v1.z + v1.w*v1.w;
    __shared__ float red[256];
    red[tid] = ss; __syncthreads();
    for (int s = 128; s > 0; s >>= 1) { if (tid < s) red[tid] += red[tid+s]; __syncthreads(); }
    if (tid == 0) norms[row] = sqrtf(red[0]);
}

// ---------------- kernel 2: outputs = inputs @ V^T ----------------
// Barrier-light streaming GEMM. Grid: 512 blocks x 512 thr (8 waves).
// Block = (m-quarter 64 rows) x (n-slab 128 cols); wave = 64 rows x 16 cols.
// A: LDS per K-phase (512), staged once, regs-prefetched. B: direct global->VGPR,
// fp32->bf16 inline. No barriers inside the 16-step phase loop.
#define BMG 64
#define PHK 512            // K per phase
#define NPH (F_SZ / PHK)   // 4 phases
#define KCP (PHK / 8)      // 64 16B-chunks per phase per row
#define LDA 520            // plane stride in shorts: 64 rows * 8 + 8 pad

__global__ __launch_bounds__(512, 4) void gemm_kernel(const unsigned short* __restrict__ Abf,
                                                      const float* __restrict__ V,
                                                      float* __restrict__ Cout,
                                                      float* __restrict__ pmax,
                                                      float* __restrict__ psum) {
    __shared__ unsigned short As[KCP * LDA];   // ~65 KB: As[kc*LDA + row*8]
    __shared__ float sm[BMG * 8], ss2[BMG * 8];

    const int tid = threadIdx.x;
    const int lane = tid & 63;
    const int wv = tid >> 6;            // 0..7
    const int q = lane >> 4, l16 = lane & 15;
    const int m0 = (blockIdx.x & 3) * BMG;      // m-variant -> different XCDs for same slab
    const int slab = blockIdx.x >> 2;           // 0..127
    const int n0 = slab * 128 + wv * 16;

    f32x4 acc[4];
    #pragma unroll
    for (int i = 0; i < 4; i++) acc[i] = (f32x4){0.f, 0.f, 0.f, 0.f};

    // staging map: r = tid>>3 (0..63), c8 = tid&7; chunks kc = c8 + 8j, j=0..7
    const int sr = tid >> 3, sc8 = tid & 7;
    const unsigned short* AgBase = Abf + (size_t)(m0 + sr) * F_SZ;

    // phase 0: direct stage to LDS
    #pragma unroll
    for (int j = 0; j < 8; ++j) {
        const int kc = sc8 + 8 * j;
        us8 v = *(const us8*)(AgBase + kc * 8);
        *(us8*)&As[kc * LDA + sr * 8] = v;
    }
    __syncthreads();

    const float* bvp = V + (size_t)(n0 + l16) * F_SZ + q * 8;
    us8 areg[8];

    for (int ph = 0; ph < NPH; ++ph) {
        // prefetch next phase's A into registers (overlaps with compute below)
        if (ph + 1 < NPH) {
            #pragma unroll
            for (int j = 0; j < 8; ++j) {
                const int kc = sc8 + 8 * j;
                areg[j] = *(const us8*)(AgBase + (ph + 1) * PHK + kc * 8);
            }
        }
        // compute: 16 k-steps of 32, no barriers
        #pragma unroll 4
        for (int ks = 0; ks < 16; ++ks) {
            const int off = ph * PHK + ks * 32;
            float4 x0 = *(const float4*)(bvp + off);
            float4 x1 = *(const float4*)(bvp + off + 4);
            union { us8 u; bf16x8 b; } cv;
            cv.u[0]=f2bf(x0.x); cv.u[1]=f2bf(x0.y); cv.u[2]=f2bf(x0.z); cv.u[3]=f2bf(x0.w);
            cv.u[4]=f2bf(x1.x); cv.u[5]=f2bf(x1.y); cv.u[6]=f2bf(x1.z); cv.u[7]=f2bf(x1.w);
            const int kc = ks * 4 + q;
            #pragma unroll
            for (int mi = 0; mi < 4; ++mi) {
                bf16x8 af = *(const bf16x8*)&As[kc * LDA + (mi * 16 + l16) * 8];
                acc[mi] = __builtin_amdgcn_mfma_f32_16x16x32_bf16(af, cv.b, acc[mi], 0, 0, 0);
            }
        }
        __syncthreads();     // all waves done reading As for this phase
        if (ph + 1 < NPH) {
            #pragma unroll
            for (int j = 0; j < 8; ++j)
                *(us8*)&As[(sc8 + 8 * j) * LDA + sr * 8] = areg[j];
            __syncthreads();
        }
    }

    // epilogue: D row=(lane>>4)*4+reg, col=lane&15  [verified m89/m91]
    #pragma unroll
    for (int mi = 0; mi < 4; ++mi) {
        const int r0 = m0 + mi * 16 + q * 4;
        const int c0 = n0 + l16;
        #pragma unroll
        for (int r = 0; r < 4; ++r)
            Cout[(size_t)(r0 + r) * C_SZ + c0] = acc[mi][r];
    }

    // per-wave softmax partials over 16 cols -> LDS -> block reduce over 8 waves
    #pragma unroll
    for (int mi = 0; mi < 4; ++mi) {
        #pragma unroll
        for (int r = 0; r < 4; ++r) {
            float mloc = acc[mi][r];
            #pragma unroll
            for (int off = 1; off < 16; off <<= 1)
                mloc = fmaxf(mloc, __shfl_xor(mloc, off, 64));
            float sloc = __expf(acc[mi][r] - mloc);
            #pragma unroll
            for (int off = 1; off < 16; off <<= 1)
                sloc += __shfl_xor(sloc, off, 64);
            if (l16 == 0) {
                const int lrow = mi * 16 + q * 4 + r;
                sm[lrow * 8 + wv] = mloc;
                ss2[lrow * 8 + wv] = sloc;
            }
        }
    }
    __syncthreads();
    if (tid < BMG) {
        float m = -INFINITY, s = 0.f;
        #pragma unroll
        for (int w = 0; w < 8; ++w) {
            float m2 = sm[tid * 8 + w], s2 = ss2[tid * 8 + w];
            float nm = fmaxf(m, m2);
            s = s * __expf(m - nm) + s2 * __expf(m2 - nm);
            m = nm;
        }
        pmax[(m0 + tid) * NTILE + slab] = m;
        psum[(m0 + tid) * NTILE + slab] = s;
    }
}

// ---------------- kernel 3: merge softmax partials -> bu_part ----------------
__global__ __launch_bounds__(128) void softmax_combine_kernel(
    const float* __restrict__ pmax, const float* __restrict__ psum,
    const float* __restrict__ outputs, const int* __restrict__ targets,
    float* __restrict__ bu_part)
{
    const int row = blockIdx.x;
    const int tid = threadIdx.x;
    __shared__ float rm[128], rs[128];
    rm[tid] = pmax[row * NTILE + tid];
    rs[tid] = psum[row * NTILE + tid];
    __syncthreads();
    for (int s = 64; s > 0; s >>= 1) {
        if (tid < s) {
            float a = rm[tid], sa = rs[tid];
            float b = rm[tid + s], sb = rs[tid + s];
            float nn = fmaxf(a, b);
            rs[tid] = sa * __expf(a - nn) + sb * __expf(b - nn);
            rm[tid] = nn;
        }
        __syncthreads();
    }
    if (tid == 0) {
        float logZ = rm[0] + logf(rs[0]);
        bu_part[row] = -(outputs[(size_t)row * C_SZ + targets[row]] - logZ);
    }
}

// ---------------- kernel 4: pair matching + sims + hard-pair sums ----------------
__global__ __launch_bounds__(256) void pairs_kernel(
    const float* __restrict__ inputs, const int* __restrict__ targets,
    const int* __restrict__ ppairs, const int* __restrict__ npairs,
    const int* __restrict__ indexs, const int* __restrict__ cluster,
    const float* __restrict__ outputs, const float* __restrict__ norms,
    float* __restrict__ hp_part, float* __restrict__ hn_part,
    int* __restrict__ flag_part)
{
    const int i = blockIdx.x;
    const int tid = threadIdx.x;
    __shared__ int idxbuf[B_SZ];
    __shared__ int pj[P_SZ];
    __shared__ int nj[N_SZ];
    __shared__ float simp[P_SZ];
    __shared__ float simn[N_SZ];
    __shared__ float tnv[N_SZ];
    __shared__ float s_tp;

    idxbuf[tid] = indexs[tid];
    __syncthreads();

    const float* row = outputs + (size_t)i * C_SZ;
    const float ni_norm = norms[i];

    // pair matching (indexs is a permutation -> at most one match; argmax = first)
    if (tid < P_SZ) {
        int pp = ppairs[i * P_SZ + tid];
        int f = -1;
        if (pp >= 0) for (int j = 0; j < B_SZ; j++) if (idxbuf[j] == pp) { f = j; break; }
        pj[tid] = f;
    } else if (tid < P_SZ + N_SZ) {
        int t = tid - P_SZ;
        int np = npairs[i * N_SZ + t];
        int f = -1;
        if (np >= 0) for (int j = 0; j < B_SZ; j++) if (idxbuf[j] == np) { f = j; break; }
        nj[t] = f;
        int cid = cluster[np < 0 ? 0 : np];           // jnp.clip(npairs, 0)
        tnv[t] = row[cid] / ni_norm;                  // tsims[i, ncid] = outputs/norm
    }
    if (tid == P_SZ + N_SZ) s_tp = row[targets[i]] / ni_norm;
    __syncthreads();

    // in-batch sims (fp32, exact semantics incl. self-match ~1.0): one pair per wave round-robin
    const int lane = tid & 63, wv = tid >> 6;
    for (int qq = wv; qq < P_SZ + N_SZ; qq += 4) {
        int j = (qq < P_SZ) ? pj[qq] : nj[qq - P_SZ];
        float s = 0.f;
        if (j >= 0) {
            const float* xi = inputs + (size_t)i * F_SZ;
            const float* xj = inputs + (size_t)j * F_SZ;
            float d = 0.f;
            for (int k = lane; k < F_SZ; k += 64) d += xi[k] * xj[k];
            for (int off = 32; off > 0; off >>= 1) d += __shfl_down(d, off);
            s = d / (ni_norm * norms[j]);
        }
        if (lane == 0) { if (qq < P_SZ) simp[qq] = s; else simn[qq - P_SZ] = s; }
    }
    __syncthreads();

    if (tid == 0) {
        float psims[P_SZ + 1]; bool pmask[P_SZ + 1];
        for (int p = 0; p < P_SZ; p++) {
            int pp = ppairs[i * P_SZ + p];
            pmask[p] = (pj[p] >= 0) && (pp >= 0);
            psims[p] = simp[p];
        }
        psims[P_SZ] = s_tp; pmask[P_SZ] = (s_tp != 0.0f);

        float nsims[2 * N_SZ]; bool nmask[2 * N_SZ];
        for (int t = 0; t < N_SZ; t++) {
            int np = npairs[i * N_SZ + t];
            nmask[t] = (nj[t] >= 0) && (np >= 0);
            nsims[t] = simn[t];
            nsims[N_SZ + t] = tnv[t];
            nmask[N_SZ + t] = (np >= 0) && (tnv[t] != 0.0f);
        }
        bool anyp = false, anyn = false;
        float maxn = -INFINITY, minp = INFINITY;
        for (int t = 0; t < 2 * N_SZ; t++) if (nmask[t]) { anyn = true; maxn = fmaxf(maxn, nsims[t]); }
        for (int p = 0; p < P_SZ + 1; p++) if (pmask[p]) { anyp = true; minp = fminf(minp, psims[p]); }
        float p_thrd = (anyn ? maxn : -3.0f) + 0.1f;
        float n_thrd = (anyp ? minp : 3.0f) - 0.1f;
        float hps = 0.f, hns = 0.f; int fl = 0;
        for (int p = 0; p < P_SZ + 1; p++)
            if (pmask[p] && psims[p] < p_thrd) { fl |= 1; hps += expf(-2.0f * (psims[p] - 0.5f)); }
        for (int t = 0; t < 2 * N_SZ; t++)
            if (nmask[t] && nsims[t] > n_thrd && nsims[t] < 0.999999f) { fl |= 2; hns += expf(50.0f * (nsims[t] - 0.5f)); }
        hp_part[i] = hps; hn_part[i] = hns; flag_part[i] = fl;
    }
}

// ---------------- kernel 5: final scalar reduce ----------------
__global__ __launch_bounds__(256) void finalize_kernel(
    const float* __restrict__ bu_part, const float* __restrict__ hp_part,
    const float* __restrict__ hn_part, const int* __restrict__ flag_part,
    float* __restrict__ d_out)
{
    __shared__ float r1[256], r2[256], r3[256];
    __shared__ int rf[256];
    const int tid = threadIdx.x;
    r1[tid] = bu_part[tid]; r2[tid] = hp_part[tid]; r3[tid] = hn_part[tid]; rf[tid] = flag_part[tid];
    __syncthreads();
    for (int s = 128; s > 0; s >>= 1) {
        if (tid < s) { r1[tid] += r1[tid+s]; r2[tid] += r2[tid+s]; r3[tid] += r3[tid+s]; rf[tid] |= rf[tid+s]; }
        __syncthreads();
    }
    if (tid == 0) {
        float bu = r1[0] / (float)B_SZ;
        float hp_loss = (rf[0] & 1) ? 0.5f * log1pf(r2[0]) : 0.0f;
        float hn_loss = (rf[0] & 2) ? (1.0f / 50.0f) * log1pf(r3[0]) : 0.0f;
        d_out[0] = 1.0f * bu + 10.0f * (hp_loss + hn_loss);   // W_BU=1, W_H=10
    }
}

extern "C" void kernel_launch(void* const* d_in, const int* in_sizes, int n_in,
                              void* d_out, int out_size, void* d_ws, size_t ws_size,
                              hipStream_t stream) {
    const float* inputs  = (const float*)d_in[0];
    const int*   targets = (const int*)d_in[1];
    const int*   ppairs  = (const int*)d_in[2];
    const int*   npairs  = (const int*)d_in[3];
    const int*   indexs  = (const int*)d_in[4];
    const int*   cluster = (const int*)d_in[5];
    const float* V       = (const float*)d_in[6];
    float* out = (float*)d_out;           // [0] = loss, [1..] = outputs row-major [B][C]

    char* ws = (char*)d_ws;
    unsigned short* Abf = (unsigned short*)ws;                       // 1 MB
    float* norms   = (float*)(ws + (size_t)B_SZ * F_SZ * 2);
    float* bu_part = norms + B_SZ;
    float* hp_part = bu_part + B_SZ;
    float* hn_part = hp_part + B_SZ;
    int*   flag_part = (int*)(hn_part + B_SZ);
    float* pmax = (float*)(flag_part + B_SZ);                        // 128 KB
    float* psum = pmax + (size_t)B_SZ * NTILE;                       // 128 KB

    prep_kernel<<<B_SZ, 256, 0, stream>>>(inputs, Abf, norms);
    gemm_kernel<<<512, 512, 0, stream>>>(Abf, V, out + 1, pmax, psum);
    softmax_combine_kernel<<<B_SZ, 128, 0, stream>>>(pmax, psum, out + 1, targets, bu_part);
    pairs_kernel<<<B_SZ, 256, 0, stream>>>(inputs, targets, ppairs, npairs, indexs,
                                           cluster, out + 1, norms,
                                           hp_part, hn_part, flag_part);
    finalize_kernel<<<1, 256, 0, stream>>>(bu_part, hp_part, hn_part, flag_part, out);
}

// Round 6
// 300.624 us; speedup vs baseline: 1.2385x; 1.2385x over previous
//
#include <hip/hip_runtime.h>
#include <hip/hip_bf16.h>
#include <math.h>

#define B_SZ 256
#define F_SZ 2048
#define C_SZ 16384
#define P_SZ 8
#define N_SZ 32
#define NTILE 256   // C_SZ / BN softmax partials per row

typedef __bf16 bf16x8 __attribute__((ext_vector_type(8)));
typedef float f32x4 __attribute__((ext_vector_type(4)));
typedef unsigned short us8 __attribute__((ext_vector_type(8)));

typedef __attribute__((address_space(3))) unsigned int lds_u32;
typedef __attribute__((address_space(1))) const unsigned int glb_u32;

// s_waitcnt immediates (gfx9 encoding): vm[3:0],[15:14]; exp[6:4]; lgkm[11:8]
#define WAITCNT_VM4   0x0F74   // vmcnt(4), exp/lgkm ignored
#define WAITCNT_VM0   0x0F70   // vmcnt(0), exp/lgkm ignored
#define WAITCNT_LGKM0 0xC07F   // lgkmcnt(0), vm/exp ignored

__device__ __forceinline__ unsigned short f2bf(float x) {
    union { float f; unsigned int u; } v; v.f = x;
    unsigned int r = v.u + 0x7FFFu + ((v.u >> 16) & 1u);  // RTN-even
    return (unsigned short)(r >> 16);
}

// ---------------- kernel 1: row norms + bf16 cast of inputs ----------------
__global__ __launch_bounds__(256) void prep_kernel(const float* __restrict__ inputs,
                                                   unsigned short* __restrict__ Abf,
                                                   float* __restrict__ norms) {
    const int row = blockIdx.x;
    const int tid = threadIdx.x;
    const float* rp = inputs + (size_t)row * F_SZ + tid * 8;
    float4 v0 = *(const float4*)(rp);
    float4 v1 = *(const float4*)(rp + 4);
    us8 o;
    o[0]=f2bf(v0.x); o[1]=f2bf(v0.y); o[2]=f2bf(v0.z); o[3]=f2bf(v0.w);
    o[4]=f2bf(v1.x); o[5]=f2bf(v1.y); o[6]=f2bf(v1.z); o[7]=f2bf(v1.w);
    *(us8*)(Abf + (size_t)row * F_SZ + tid * 8) = o;
    float ss = v0.x*v0.x + v0.y*v0.y + v0.z*v0.z + v0.w*v0.w
             + v1.x*v1.x + v1.y*v1.y + v1.z*v1.z + v1.w*v1.w;
    __shared__ float red[256];
    red[tid] = ss; __syncthreads();
    for (int s = 128; s > 0; s >>= 1) { if (tid < s) red[tid] += red[tid+s]; __syncthreads(); }
    if (tid == 0) norms[row] = sqrtf(red[0]);
}

// ---------------- kernel 2: outputs = inputs @ V^T ----------------
// BM=128, BN=64, BK=64, 256 thr (4 waves as 2m x 2n; wave tile 64x32).
// Pipelined K-loop: A = 3-deep LDS ring via global_load_lds issued 2 iters
// ahead; B = fp32->VGPR->bf16->LDS dbuf issued 1 iter ahead. Raw s_barrier +
// manual s_waitcnt vmcnt(4): A(it+2) stays in flight across the barrier.
#define BM 128
#define BN 64
#define BK 64
#define BPAD 72
#define KITERS (F_SZ / BK)   // 32

__global__ __launch_bounds__(256, 2) void gemm_kernel(const unsigned short* __restrict__ Abf,
                                                      const float* __restrict__ V,
                                                      float* __restrict__ Cout,
                                                      float* __restrict__ pmax,
                                                      float* __restrict__ psum) {
    __shared__ unsigned short As[3][BM * BK];    // 3 x 16 KB ring, swizzled
    __shared__ unsigned short Bs[2][BN * BPAD];  // 2 x 9 KB, padded
    __shared__ float sm[BM * 2], ss2[BM * 2];

    const int tid = threadIdx.x;
    const int lane = tid & 63;
    const int wid = tid >> 6;
    const int wm = wid >> 1, wn = wid & 1;       // 2 m-waves x 2 n-waves
    const int q = lane >> 4, l16 = lane & 15;

    // block mapping: same-slab m-pair 8 ids apart -> same XCD L2 for V reuse
    const int bid = blockIdx.x;
    const int mhalf = (bid >> 3) & 1;
    const int slab  = (bid & 7) | ((bid >> 4) << 3);
    const int bm0 = mhalf * BM;
    const int bn0 = slab * BN;

    f32x4 acc[4][2];
    #pragma unroll
    for (int i = 0; i < 4; i++)
        #pragma unroll
        for (int j = 0; j < 2; j++) acc[i][j] = (f32x4){0.f, 0.f, 0.f, 0.f};

    // ---- A staging map: slot s = j*256 + tid; row = j*32 + (tid>>3),
    //      stored chunk c = tid&7 holds global chunk kc = c ^ (row&7).
    const int arow = tid >> 3;
    const int akc = (tid & 7) ^ (arow & 7);
    const unsigned short* AgBase = Abf + (size_t)(bm0 + arow) * F_SZ + akc * 8;

    // ---- B staging: thread -> (col = tid>>2, seg = tid&3), 16 fp32 each
    const int bcol = tid >> 2, bseg = tid & 3;
    const float* BgBase = V + (size_t)(bn0 + bcol) * F_SZ + bseg * 16;
    const int bsoff = bcol * BPAD + bseg * 16;

    float4 b0, b1, b2, b3;

    auto issueA = [&](int ring, int k0) {
        #pragma unroll
        for (int j = 0; j < 4; ++j) {
            __builtin_amdgcn_global_load_lds(
                (glb_u32*)(AgBase + (size_t)j * 32 * F_SZ + k0),
                (lds_u32*)&As[ring][(j * 256 + wid * 64) * 8],
                16, 0, 0);
        }
    };
    auto loadB = [&](int k0) {
        b0 = *(const float4*)(BgBase + k0);
        b1 = *(const float4*)(BgBase + k0 + 4);
        b2 = *(const float4*)(BgBase + k0 + 8);
        b3 = *(const float4*)(BgBase + k0 + 12);
    };
    auto writeB = [&](int buf) {
        us8 w0, w1;
        w0[0]=f2bf(b0.x); w0[1]=f2bf(b0.y); w0[2]=f2bf(b0.z); w0[3]=f2bf(b0.w);
        w0[4]=f2bf(b1.x); w0[5]=f2bf(b1.y); w0[6]=f2bf(b1.z); w0[7]=f2bf(b1.w);
        w1[0]=f2bf(b2.x); w1[1]=f2bf(b2.y); w1[2]=f2bf(b2.z); w1[3]=f2bf(b2.w);
        w1[4]=f2bf(b3.x); w1[5]=f2bf(b3.y); w1[6]=f2bf(b3.z); w1[7]=f2bf(b3.w);
        *(us8*)&Bs[buf][bsoff] = w0;
        *(us8*)&Bs[buf][bsoff + 8] = w1;
    };
    auto compute = [&](int ring, int buf) {
        #pragma unroll
        for (int ks = 0; ks < 2; ++ks) {
            bf16x8 af[4], bfv[2];
            const int kc = ks * 4 + q;
            #pragma unroll
            for (int mi = 0; mi < 4; ++mi) {
                const int row = wm * 64 + mi * 16 + l16;
                af[mi] = *(const bf16x8*)&As[ring][row * 64 + (kc ^ (row & 7)) * 8];
            }
            #pragma unroll
            for (int ni = 0; ni < 2; ++ni) {
                const int col = wn * 32 + ni * 16 + l16;
                bfv[ni] = *(const bf16x8*)&Bs[buf][col * BPAD + ks * 32 + q * 8];
            }
            #pragma unroll
            for (int mi = 0; mi < 4; ++mi)
                #pragma unroll
                for (int ni = 0; ni < 2; ++ni)
                    acc[mi][ni] = __builtin_amdgcn_mfma_f32_16x16x32_bf16(af[mi], bfv[ni], acc[mi][ni], 0, 0, 0);
        }
    };

    // prologue: A(0)->ring0, A(1)->ring1, B(0)->Bs[0]
    issueA(0, 0);
    issueA(1, BK);
    loadB(0);
    __builtin_amdgcn_s_waitcnt(WAITCNT_VM0);
    writeB(0);
    __syncthreads();

    int cur = 0;                        // it % 3
    int nxt2 = 2;                       // (it+2) % 3
    #pragma unroll 1
    for (int it = 0; it < KITERS; ++it) {
        if (it + 1 < KITERS) loadB((it + 1) * BK);     // 4 vm loads
        if (it + 2 < KITERS) issueA(nxt2, (it + 2) * BK); // 4 glds
        compute(cur, it & 1);
        // drain A(it+1)+B(it+1) (oldest 8); keep A(it+2) (newest 4) in flight
        if (it + 2 < KITERS)      __builtin_amdgcn_s_waitcnt(WAITCNT_VM4);
        else if (it + 1 < KITERS) __builtin_amdgcn_s_waitcnt(WAITCNT_VM0);
        if (it + 1 < KITERS) {
            writeB((it + 1) & 1);
            __builtin_amdgcn_s_waitcnt(WAITCNT_LGKM0);  // ds_writes visible
            __builtin_amdgcn_s_barrier();               // raw: no vmcnt drain
        }
        cur  = (cur == 2) ? 0 : cur + 1;
        nxt2 = (nxt2 == 2) ? 0 : nxt2 + 1;
    }

    // epilogue: D row=(lane>>4)*4+reg, col=lane&15  [verified m89/m91]
    #pragma unroll
    for (int mi = 0; mi < 4; ++mi) {
        const int r0 = bm0 + wm * 64 + mi * 16 + q * 4;
        #pragma unroll
        for (int ni = 0; ni < 2; ++ni) {
            const int c0 = bn0 + wn * 32 + ni * 16 + l16;
            #pragma unroll
            for (int r = 0; r < 4; ++r)
                Cout[(size_t)(r0 + r) * C_SZ + c0] = acc[mi][ni][r];
        }
    }

    // fused partial softmax over this block's 64 cols (per wave: 32 cols)
    #pragma unroll
    for (int mi = 0; mi < 4; ++mi) {
        #pragma unroll
        for (int r = 0; r < 4; ++r) {
            float mloc = fmaxf(acc[mi][0][r], acc[mi][1][r]);
            #pragma unroll
            for (int off = 1; off < 16; off <<= 1)
                mloc = fmaxf(mloc, __shfl_xor(mloc, off, 64));
            float sloc = __expf(acc[mi][0][r] - mloc) + __expf(acc[mi][1][r] - mloc);
            #pragma unroll
            for (int off = 1; off < 16; off <<= 1)
                sloc += __shfl_xor(sloc, off, 64);
            if (l16 == 0) {
                const int lrow = wm * 64 + mi * 16 + q * 4 + r;
                sm[lrow * 2 + wn] = mloc;
                ss2[lrow * 2 + wn] = sloc;
            }
        }
    }
    __syncthreads();
    if (tid < BM) {
        float m1 = sm[tid * 2], s1 = ss2[tid * 2];
        float m2 = sm[tid * 2 + 1], s2 = ss2[tid * 2 + 1];
        float nm = fmaxf(m1, m2);
        float s = s1 * __expf(m1 - nm) + s2 * __expf(m2 - nm);
        pmax[(bm0 + tid) * NTILE + slab] = nm;
        psum[(bm0 + tid) * NTILE + slab] = s;
    }
}

// ---------------- kernel 3: merge softmax partials -> bu_part ----------------
__global__ __launch_bounds__(256) void softmax_combine_kernel(
    const float* __restrict__ pmax, const float* __restrict__ psum,
    const float* __restrict__ outputs, const int* __restrict__ targets,
    float* __restrict__ bu_part)
{
    const int row = blockIdx.x;
    const int tid = threadIdx.x;
    __shared__ float rm[256], rs[256];
    rm[tid] = pmax[row * NTILE + tid];
    rs[tid] = psum[row * NTILE + tid];
    __syncthreads();
    for (int s = 128; s > 0; s >>= 1) {
        if (tid < s) {
            float a = rm[tid], sa = rs[tid];
            float b = rm[tid + s], sb = rs[tid + s];
            float nn = fmaxf(a, b);
            rs[tid] = sa * __expf(a - nn) + sb * __expf(b - nn);
            rm[tid] = nn;
        }
        __syncthreads();
    }
    if (tid == 0) {
        float logZ = rm[0] + logf(rs[0]);
        bu_part[row] = -(outputs[(size_t)row * C_SZ + targets[row]] - logZ);
    }
}

// ---------------- kernel 4: pair matching + sims + hard-pair sums ----------------
__global__ __launch_bounds__(256) void pairs_kernel(
    const float* __restrict__ inputs, const int* __restrict__ targets,
    const int* __restrict__ ppairs, const int* __restrict__ npairs,
    const int* __restrict__ indexs, const int* __restrict__ cluster,
    const float* __restrict__ outputs, const float* __restrict__ norms,
    float* __restrict__ hp_part, float* __restrict__ hn_part,
    int* __restrict__ flag_part)
{
    const int i = blockIdx.x;
    const int tid = threadIdx.x;
    __shared__ int idxbuf[B_SZ];
    __shared__ int pj[P_SZ];
    __shared__ int nj[N_SZ];
    __shared__ float simp[P_SZ];
    __shared__ float simn[N_SZ];
    __shared__ float tnv[N_SZ];
    __shared__ float s_tp;

    idxbuf[tid] = indexs[tid];
    __syncthreads();

    const float* row = outputs + (size_t)i * C_SZ;
    const float ni_norm = norms[i];

    // pair matching (indexs is a permutation -> at most one match; argmax = first)
    if (tid < P_SZ) {
        int pp = ppairs[i * P_SZ + tid];
        int f = -1;
        if (pp >= 0) for (int j = 0; j < B_SZ; j++) if (idxbuf[j] == pp) { f = j; break; }
        pj[tid] = f;
    } else if (tid < P_SZ + N_SZ) {
        int t = tid - P_SZ;
        int np = npairs[i * N_SZ + t];
        int f = -1;
        if (np >= 0) for (int j = 0; j < B_SZ; j++) if (idxbuf[j] == np) { f = j; break; }
        nj[t] = f;
        int cid = cluster[np < 0 ? 0 : np];           // jnp.clip(npairs, 0)
        tnv[t] = row[cid] / ni_norm;                  // tsims[i, ncid] = outputs/norm
    }
    if (tid == P_SZ + N_SZ) s_tp = row[targets[i]] / ni_norm;
    __syncthreads();

    // in-batch sims (fp32, exact semantics incl. self-match ~1.0): one pair per wave round-robin
    const int lane = tid & 63, wv = tid >> 6;
    for (int qq = wv; qq < P_SZ + N_SZ; qq += 4) {
        int j = (qq < P_SZ) ? pj[qq] : nj[qq - P_SZ];
        float s = 0.f;
        if (j >= 0) {
            const float* xi = inputs + (size_t)i * F_SZ;
            const float* xj = inputs + (size_t)j * F_SZ;
            float d = 0.f;
            for (int k = lane; k < F_SZ; k += 64) d += xi[k] * xj[k];
            for (int off = 32; off > 0; off >>= 1) d += __shfl_down(d, off);
            s = d / (ni_norm * norms[j]);
        }
        if (lane == 0) { if (qq < P_SZ) simp[qq] = s; else simn[qq - P_SZ] = s; }
    }
    __syncthreads();

    if (tid == 0) {
        float psims[P_SZ + 1]; bool pmask[P_SZ + 1];
        for (int p = 0; p < P_SZ; p++) {
            int pp = ppairs[i * P_SZ + p];
            pmask[p] = (pj[p] >= 0) && (pp >= 0);
            psims[p] = simp[p];
        }
        psims[P_SZ] = s_tp; pmask[P_SZ] = (s_tp != 0.0f);

        float nsims[2 * N_SZ]; bool nmask[2 * N_SZ];
        for (int t = 0; t < N_SZ; t++) {
            int np = npairs[i * N_SZ + t];
            nmask[t] = (nj[t] >= 0) && (np >= 0);
            nsims[t] = simn[t];
            nsims[N_SZ + t] = tnv[t];
            nmask[N_SZ + t] = (np >= 0) && (tnv[t] != 0.0f);
        }
        bool anyp = false, anyn = false;
        float maxn = -INFINITY, minp = INFINITY;
        for (int t = 0; t < 2 * N_SZ; t++) if (nmask[t]) { anyn = true; maxn = fmaxf(maxn, nsims[t]); }
        for (int p = 0; p < P_SZ + 1; p++) if (pmask[p]) { anyp = true; minp = fminf(minp, psims[p]); }
        float p_thrd = (anyn ? maxn : -3.0f) + 0.1f;
        float n_thrd = (anyp ? minp : 3.0f) - 0.1f;
        float hps = 0.f, hns = 0.f; int fl = 0;
        for (int p = 0; p < P_SZ + 1; p++)
            if (pmask[p] && psims[p] < p_thrd) { fl |= 1; hps += expf(-2.0f * (psims[p] - 0.5f)); }
        for (int t = 0; t < 2 * N_SZ; t++)
            if (nmask[t] && nsims[t] > n_thrd && nsims[t] < 0.999999f) { fl |= 2; hns += expf(50.0f * (nsims[t] - 0.5f)); }
        hp_part[i] = hps; hn_part[i] = hns; flag_part[i] = fl;
    }
}

// ---------------- kernel 5: final scalar reduce ----------------
__global__ __launch_bounds__(256) void finalize_kernel(
    const float* __restrict__ bu_part, const float* __restrict__ hp_part,
    const float* __restrict__ hn_part, const int* __restrict__ flag_part,
    float* __restrict__ d_out)
{
    __shared__ float r1[256], r2[256], r3[256];
    __shared__ int rf[256];
    const int tid = threadIdx.x;
    r1[tid] = bu_part[tid]; r2[tid] = hp_part[tid]; r3[tid] = hn_part[tid]; rf[tid] = flag_part[tid];
    __syncthreads();
    for (int s = 128; s > 0; s >>= 1) {
        if (tid < s) { r1[tid] += r1[tid+s]; r2[tid] += r2[tid+s]; r3[tid] += r3[tid+s]; rf[tid] |= rf[tid+s]; }
        __syncthreads();
    }
    if (tid == 0) {
        float bu = r1[0] / (float)B_SZ;
        float hp_loss = (rf[0] & 1) ? 0.5f * log1pf(r2[0]) : 0.0f;
        float hn_loss = (rf[0] & 2) ? (1.0f / 50.0f) * log1pf(r3[0]) : 0.0f;
        d_out[0] = 1.0f * bu + 10.0f * (hp_loss + hn_loss);   // W_BU=1, W_H=10
    }
}

extern "C" void kernel_launch(void* const* d_in, const int* in_sizes, int n_in,
                              void* d_out, int out_size, void* d_ws, size_t ws_size,
                              hipStream_t stream) {
    const float* inputs  = (const float*)d_in[0];
    const int*   targets = (const int*)d_in[1];
    const int*   ppairs  = (const int*)d_in[2];
    const int*   npairs  = (const int*)d_in[3];
    const int*   indexs  = (const int*)d_in[4];
    const int*   cluster = (const int*)d_in[5];
    const float* V       = (const float*)d_in[6];
    float* out = (float*)d_out;           // [0] = loss, [1..] = outputs row-major [B][C]

    char* ws = (char*)d_ws;
    unsigned short* Abf = (unsigned short*)ws;                       // 1 MB
    float* norms   = (float*)(ws + (size_t)B_SZ * F_SZ * 2);
    float* bu_part = norms + B_SZ;
    float* hp_part = bu_part + B_SZ;
    float* hn_part = hp_part + B_SZ;
    int*   flag_part = (int*)(hn_part + B_SZ);
    float* pmax = (float*)(flag_part + B_SZ);                        // 256 KB
    float* psum = pmax + (size_t)B_SZ * NTILE;                       // 256 KB

    prep_kernel<<<B_SZ, 256, 0, stream>>>(inputs, Abf, norms);
    gemm_kernel<<<512, 256, 0, stream>>>(Abf, V, out + 1, pmax, psum);
    softmax_combine_kernel<<<B_SZ, 256, 0, stream>>>(pmax, psum, out + 1, targets, bu_part);
    pairs_kernel<<<B_SZ, 256, 0, stream>>>(inputs, targets, ppairs, npairs, indexs,
                                           cluster, out + 1, norms,
                                           hp_part, hn_part, flag_part);
    finalize_kernel<<<1, 256, 0, stream>>>(bu_part, hp_part, hn_part, flag_part, out);
}